// Round 7
// baseline (589.626 us; speedup 1.0000x reference)
//
#include <hip/hip_runtime.h>
#include <hip/hip_bf16.h>
#include <stdint.h>

typedef __bf16 bf16_t;
typedef __bf16 bf16x4 __attribute__((ext_vector_type(4)));
typedef __bf16 bf16x8 __attribute__((ext_vector_type(8)));
typedef float  f32x4  __attribute__((ext_vector_type(4)));

#define B_  4
#define L_  2048
#define D_  1024
#define H_  16
#define DH_ 64

// async global->LDS, 16B per lane. lds ptr is wave-uniform; HW adds lane*16.
__device__ __forceinline__ void async_load16(const bf16_t* g, bf16_t* lds) {
    __builtin_amdgcn_global_load_lds(
        (__attribute__((address_space(1))) void*)g,
        (__attribute__((address_space(3))) void*)lds, 16, 0, 0);
}

// fp32 -> bf16, 4 elements/thread. n4 = n/4.
__global__ __launch_bounds__(256) void cvt_f32_bf16(
    const float* __restrict__ in, bf16_t* __restrict__ out, int n4)
{
    int i = blockIdx.x * 256 + threadIdx.x;
    if (i < n4) {
        f32x4 v = *(const f32x4*)(in + (size_t)i * 4);
        bf16x4 o;
        o[0] = (bf16_t)v[0]; o[1] = (bf16_t)v[1];
        o[2] = (bf16_t)v[2]; o[3] = (bf16_t)v[3];
        *(bf16x4*)(out + (size_t)i * 4) = o;
    }
}

// four 1M-element weights in one launch; 262144 float4-chunks per tensor
__global__ __launch_bounds__(256) void cvt4_f32_bf16(
    const float* __restrict__ w0, const float* __restrict__ w1,
    const float* __restrict__ w2, const float* __restrict__ w3,
    bf16_t* __restrict__ o0, bf16_t* __restrict__ o1,
    bf16_t* __restrict__ o2, bf16_t* __restrict__ o3)
{
    int i = blockIdx.x * 256 + threadIdx.x;          // 0 .. 4*262144-1
    int which = i >> 18;
    int j = (i & 262143) * 4;
    const float* w = which == 0 ? w0 : which == 1 ? w1 : which == 2 ? w2 : w3;
    bf16_t*      o = which == 0 ? o0 : which == 1 ? o1 : which == 2 ? o2 : o3;
    f32x4 v = *(const f32x4*)(w + j);
    bf16x4 ov;
    ov[0] = (bf16_t)v[0]; ov[1] = (bf16_t)v[1];
    ov[2] = (bf16_t)v[2]; ov[3] = (bf16_t)v[3];
    *(bf16x4*)(o + j) = ov;
}

// C[M,N] = A[M,K] * B[N,K]^T, bf16 in, fp32 accum. 128x128 tile, 4 waves
// (2x2 of 64x64), 16x16x32 bf16 MFMA.
// mode 0: bf16 row-major out (Cb). mode 1: bf16 scatter as Vt[B][H][DH][S]
// (Cb). mode 2: fp32 row-major out (Cf) — for the final projection.
__global__ __launch_bounds__(256) void gemm_bt(
    const bf16_t* __restrict__ A, const bf16_t* __restrict__ Bm,
    bf16_t* __restrict__ Cb, float* __restrict__ Cf,
    int M, int N, int K, int mode)
{
    __shared__ __align__(16) bf16_t lds[8192];  // A tile 128x32 | B tile 128x32
    const int t = threadIdx.x;
    const int w = t >> 6, l = t & 63;
    const int quad = l >> 4, l15 = l & 15;
    const int wm = w >> 1, wn = w & 1;
    const int rowBase = blockIdx.y * 128;
    const int colBase = blockIdx.x * 128;

    f32x4 acc[4][4] = {};

    for (int k0 = 0; k0 < K; k0 += 32) {
        #pragma unroll
        for (int q2 = 0; q2 < 2; ++q2) {
            int c = q2 * 256 + w * 64 + l;       // 16B chunk id, 0..511
            int r = c >> 2, kc = c & 3;          // row (64B = 4 chunks/row)
            async_load16(&A[(size_t)(rowBase + r) * K + k0 + kc * 8],
                         &lds[(q2 * 256 + w * 64) * 8]);
            async_load16(&Bm[(size_t)(colBase + r) * K + k0 + kc * 8],
                         &lds[4096 + (q2 * 256 + w * 64) * 8]);
        }
        __syncthreads();

        bf16x8 af[4], bfr[4];
        #pragma unroll
        for (int i = 0; i < 4; ++i) {
            af[i]  = *(const bf16x8*)&lds[(wm * 64 + i * 16 + l15) * 32 + quad * 8];
            bfr[i] = *(const bf16x8*)&lds[4096 + (wn * 64 + i * 16 + l15) * 32 + quad * 8];
        }
        #pragma unroll
        for (int mt = 0; mt < 4; ++mt)
            #pragma unroll
            for (int nt = 0; nt < 4; ++nt)
                acc[mt][nt] = __builtin_amdgcn_mfma_f32_16x16x32_bf16(
                    af[mt], bfr[nt], acc[mt][nt], 0, 0, 0);
        __syncthreads();
    }

    #pragma unroll
    for (int mt = 0; mt < 4; ++mt)
        #pragma unroll
        for (int nt = 0; nt < 4; ++nt)
            #pragma unroll
            for (int r = 0; r < 4; ++r) {
                int row = rowBase + wm * 64 + mt * 16 + quad * 4 + r;  // C/D: row=quad*4+reg
                int col = colBase + wn * 64 + nt * 16 + l15;           //      col=lane&15
                float v = acc[mt][nt][r];
                if (mode == 0) {
                    Cb[(size_t)row * N + col] = (bf16_t)v;
                } else if (mode == 1) {
                    int b = row >> 11, s = row & 2047;   // row = b*2048 + s
                    int h = col >> 6,  d = col & 63;     // col = h*64 + d
                    Cb[(((size_t)((b * H_ + h) * DH_ + d)) << 11) + s] = (bf16_t)v;
                } else {
                    Cf[(size_t)row * N + col] = v;
                }
            }
}

// Flash attention, causal. One block = (b, h, 64 Q rows); wave w owns 16 rows.
// Q:[B*L,D] (head at col h*64), K same, Vt:[B,H,DH,S]. Out: [B*L,D] bf16.
__global__ __launch_bounds__(256) void attn_fwd(
    const bf16_t* __restrict__ Qw, const bf16_t* __restrict__ Kw,
    const bf16_t* __restrict__ Vt, bf16_t* __restrict__ Ow)
{
    __shared__ __align__(16) bf16_t k_lds[4096];  // 64(s) x 64(d)
    __shared__ __align__(16) bf16_t v_lds[4096];  // 64(d) x 64(s)  (from Vt)
    __shared__ __align__(16) bf16_t p_lds[4096];  // 4 waves x 16 x 64
    const int t = threadIdx.x;
    const int w = t >> 6, l = t & 63;
    const int quad = l >> 4, l15 = l & 15;
    const int qt = gridDim.x - 1 - blockIdx.x;    // heavy blocks first
    const int h = blockIdx.y, b = blockIdx.z;

    // Q fragments, held in registers across the whole K loop.
    const bf16_t* qp = Qw + (size_t)(b * L_ + qt * 64 + w * 16 + l15) * D_ + h * DH_ + quad * 8;
    const bf16x8 aq0 = *(const bf16x8*)qp;          // k = quad*8 + j
    const bf16x8 aq1 = *(const bf16x8*)(qp + 32);   // k = 32 + quad*8 + j

    f32x4 acc[4] = {};
    float m_i[4], l_i[4];
    #pragma unroll
    for (int r = 0; r < 4; ++r) { m_i[r] = -1e30f; l_i[r] = 0.f; }

    for (int jt = 0; jt <= qt; ++jt) {
        const int j0 = jt * 64;
        #pragma unroll
        for (int q2 = 0; q2 < 2; ++q2) {
            int c = q2 * 256 + w * 64 + l;       // chunk 0..511
            int rr = c >> 3, kc = c & 7;         // 128B rows = 8 chunks
            async_load16(&Kw[(size_t)(b * L_ + j0 + rr) * D_ + h * DH_ + kc * 8],
                         &k_lds[(q2 * 256 + w * 64) * 8]);
            async_load16(&Vt[((size_t)((b * H_ + h) * DH_ + rr)) * (size_t)L_ + j0 + kc * 8],
                         &v_lds[(q2 * 256 + w * 64) * 8]);
        }
        __syncthreads();

        // S = Q * K^T   (16x64 per wave)
        f32x4 s[4] = {};
        #pragma unroll
        for (int nt = 0; nt < 4; ++nt) {
            bf16x8 bk0 = *(const bf16x8*)&k_lds[(nt * 16 + l15) * 64 + quad * 8];
            bf16x8 bk1 = *(const bf16x8*)&k_lds[(nt * 16 + l15) * 64 + 32 + quad * 8];
            s[nt] = __builtin_amdgcn_mfma_f32_16x16x32_bf16(aq0, bk0, s[nt], 0, 0, 0);
            s[nt] = __builtin_amdgcn_mfma_f32_16x16x32_bf16(aq1, bk1, s[nt], 0, 0, 0);
        }

        // scale + causal mask (only bites on the diagonal tile)
        const int rowg = qt * 64 + w * 16 + quad * 4;
        #pragma unroll
        for (int nt = 0; nt < 4; ++nt) {
            int col = j0 + nt * 16 + l15;
            #pragma unroll
            for (int r = 0; r < 4; ++r) {
                float x = s[nt][r] * 0.125f;
                s[nt][r] = (col > rowg + r) ? -1e30f : x;
            }
        }

        // online softmax; rows quad*4+r live in the 16-lane group sharing `quad`
        float mx[4];
        #pragma unroll
        for (int r = 0; r < 4; ++r)
            mx[r] = fmaxf(fmaxf(s[0][r], s[1][r]), fmaxf(s[2][r], s[3][r]));
        #pragma unroll
        for (int d = 1; d < 16; d <<= 1)
            #pragma unroll
            for (int r = 0; r < 4; ++r)
                mx[r] = fmaxf(mx[r], __shfl_xor(mx[r], d));

        float alpha[4], rs[4];
        #pragma unroll
        for (int r = 0; r < 4; ++r) {
            float mn = fmaxf(m_i[r], mx[r]);
            alpha[r] = __expf(m_i[r] - mn);
            m_i[r] = mn;
            rs[r] = 0.f;
        }
        #pragma unroll
        for (int nt = 0; nt < 4; ++nt)
            #pragma unroll
            for (int r = 0; r < 4; ++r) {
                float p = __expf(s[nt][r] - m_i[r]);
                s[nt][r] = p;
                rs[r] += p;
            }
        #pragma unroll
        for (int d = 1; d < 16; d <<= 1)
            #pragma unroll
            for (int r = 0; r < 4; ++r)
                rs[r] += __shfl_xor(rs[r], d);
        #pragma unroll
        for (int r = 0; r < 4; ++r) {
            l_i[r] = l_i[r] * alpha[r] + rs[r];
            acc[0][r] *= alpha[r]; acc[1][r] *= alpha[r];
            acc[2][r] *= alpha[r]; acc[3][r] *= alpha[r];
        }

        // P: C-layout -> LDS (16 rows x 64 cols per wave) -> A-layout frags.
        // Cross-lane dataflow through LDS: barrier REQUIRED.
        #pragma unroll
        for (int nt = 0; nt < 4; ++nt)
            #pragma unroll
            for (int r = 0; r < 4; ++r)
                p_lds[w * 1024 + (quad * 4 + r) * 64 + nt * 16 + l15] = (bf16_t)s[nt][r];
        __syncthreads();

        // O += P * V
        #pragma unroll
        for (int ks = 0; ks < 2; ++ks) {
            bf16x8 ap = *(const bf16x8*)&p_lds[w * 1024 + l15 * 64 + ks * 32 + quad * 8];
            #pragma unroll
            for (int nt = 0; nt < 4; ++nt) {
                bf16x8 bv = *(const bf16x8*)&v_lds[(nt * 16 + l15) * 64 + ks * 32 + quad * 8];
                acc[nt] = __builtin_amdgcn_mfma_f32_16x16x32_bf16(ap, bv, acc[nt], 0, 0, 0);
            }
        }
        __syncthreads();   // before restaging K/Vt and rewriting p_lds
    }

    #pragma unroll
    for (int nt = 0; nt < 4; ++nt)
        #pragma unroll
        for (int r = 0; r < 4; ++r) {
            int row = qt * 64 + w * 16 + quad * 4 + r;
            float v = acc[nt][r] / l_i[r];
            Ow[(size_t)(b * L_ + row) * D_ + h * DH_ + nt * 16 + l15] = (bf16_t)v;
        }
}

extern "C" void kernel_launch(void* const* d_in, const int* in_sizes, int n_in,
                              void* d_out, int out_size, void* d_ws, size_t ws_size,
                              hipStream_t stream)
{
    // Inputs fp32, output fp32 (reference dtypes; confirmed by R1/R6-vs-R2-R5
    // misread signatures). Compute in bf16 MFMA, final store fp32.
    const float* queries = (const float*)d_in[0];
    const float* keys    = (const float*)d_in[1];
    const float* values  = (const float*)d_in[2];
    const float* Wq = (const float*)d_in[3];
    const float* Wk = (const float*)d_in[4];
    const float* Wv = (const float*)d_in[5];
    const float* Wo = (const float*)d_in[6];
    float* out = (float*)d_out;

    const size_t SZ = (size_t)B_ * L_ * D_;   // 8,388,608
    const size_t WZ = (size_t)D_ * D_;        // 1,048,576
    bf16_t* cbuf  = (bf16_t*)d_ws;            // shared conversion buffer
    bf16_t* cWq   = cbuf + SZ;
    bf16_t* cWk   = cWq + WZ;
    bf16_t* cWv   = cWk + WZ;
    bf16_t* cWo   = cWv + WZ;
    bf16_t* q_ws  = cWo + WZ;
    bf16_t* k_ws  = q_ws + SZ;
    bf16_t* vt_ws = k_ws + SZ;                // [B,H,DH,S]
    bf16_t* a_ws  = cbuf;                     // attn out aliases cbuf (dead)

    const int n4 = (int)(SZ / 4);
    const int cblocks = n4 / 256;
    dim3 gg(D_ / 128, (B_ * L_) / 128);       // (8, 64)

    cvt4_f32_bf16<<<4096, 256, 0, stream>>>(Wq, Wk, Wv, Wo, cWq, cWk, cWv, cWo);

    cvt_f32_bf16<<<cblocks, 256, 0, stream>>>(queries, cbuf, n4);
    gemm_bt<<<gg, 256, 0, stream>>>(cbuf, cWq, q_ws,  nullptr, B_ * L_, D_, D_, 0);
    cvt_f32_bf16<<<cblocks, 256, 0, stream>>>(keys, cbuf, n4);
    gemm_bt<<<gg, 256, 0, stream>>>(cbuf, cWk, k_ws,  nullptr, B_ * L_, D_, D_, 0);
    cvt_f32_bf16<<<cblocks, 256, 0, stream>>>(values, cbuf, n4);
    gemm_bt<<<gg, 256, 0, stream>>>(cbuf, cWv, vt_ws, nullptr, B_ * L_, D_, D_, 1);

    attn_fwd<<<dim3(L_ / 64, H_, B_), 256, 0, stream>>>(q_ws, k_ws, vt_ws, a_ws);

    gemm_bt<<<gg, 256, 0, stream>>>(a_ws, cWo, nullptr, out, B_ * L_, D_, D_, 2);
}